// Round 4
// baseline (281.308 us; speedup 1.0000x reference)
//
#include <hip/hip_runtime.h>
#include <hip/hip_bf16.h>

typedef __bf16 bf16x8 __attribute__((ext_vector_type(8)));
typedef float f32x4 __attribute__((ext_vector_type(4)));

static constexpr int NN = 4096;   // nodes
static constexpr int FE = 64;     // features
static constexpr int NH = 8;      // heads
#define LOG2E 1.44269504088896340736f

// ------------------------------------------------------------------
// Kernel 1: ltg = graph @ W[h]  (fp32), store ltgT (feature-major bf16),
//           s~ = (ltg . a_src)*log2e, d~ = (ltg . a_dst)*log2e
// grid (NN/64, NH), 256 threads
// ------------------------------------------------------------------
__global__ __launch_bounds__(256) void gat_k1(
    const float* __restrict__ graph, const float* __restrict__ W,
    const float* __restrict__ a, ushort* __restrict__ ltgT,
    float* __restrict__ st, float* __restrict__ dt)
{
  const int h  = blockIdx.y;
  const int n0 = blockIdx.x * 64;
  const int t  = threadIdx.x;

  __shared__ float  Wl[64 * 68];   // Wl[f][k], padded
  __shared__ float  gT[64 * 68];   // gT[f][n], padded (graph transposed)
  __shared__ ushort lt[64 * 64];   // lt[k][n] bf16 staging for coalesced out

  const float* Wh = W + h * FE * FE;
  const int fr = t >> 2;           // row 0..63
  const int qc = (t & 3) * 16;     // col chunk
  #pragma unroll
  for (int e = 0; e < 4; e++) {
    float4 wv = *(const float4*)(Wh + fr * FE + qc + e * 4);
    *(float4*)(&Wl[fr * 68 + qc + e * 4]) = wv;
    float4 gv = *(const float4*)(graph + (n0 + fr) * FE + qc + e * 4);
    gT[(qc + e * 4 + 0) * 68 + fr] = gv.x;
    gT[(qc + e * 4 + 1) * 68 + fr] = gv.y;
    gT[(qc + e * 4 + 2) * 68 + fr] = gv.z;
    gT[(qc + e * 4 + 3) * 68 + fr] = gv.w;
  }
  __syncthreads();

  const int n4 = (t >> 4) * 4;     // 4 nodes
  const int k4 = (t & 15) * 4;     // 4 features
  float acc[4][4];
  #pragma unroll
  for (int i = 0; i < 4; i++)
    #pragma unroll
    for (int j = 0; j < 4; j++) acc[i][j] = 0.f;

  for (int f = 0; f < FE; f++) {
    f32x4 g = *(const f32x4*)(&gT[f * 68 + n4]);
    f32x4 w = *(const f32x4*)(&Wl[f * 68 + k4]);
    #pragma unroll
    for (int i = 0; i < 4; i++)
      #pragma unroll
      for (int j = 0; j < 4; j++)
        acc[i][j] = fmaf(g[i], w[j], acc[i][j]);
  }

  // s,d partials over this thread's 4 features
  float4 As = *(const float4*)(a + h * 2 * FE + k4);
  float4 Ad = *(const float4*)(a + h * 2 * FE + FE + k4);
  float sp[4], dp[4];
  #pragma unroll
  for (int i = 0; i < 4; i++) {
    sp[i] = acc[i][0] * As.x + acc[i][1] * As.y + acc[i][2] * As.z + acc[i][3] * As.w;
    dp[i] = acc[i][0] * Ad.x + acc[i][1] * Ad.y + acc[i][2] * Ad.z + acc[i][3] * Ad.w;
  }
  #pragma unroll
  for (int off = 1; off < 16; off <<= 1) {
    #pragma unroll
    for (int i = 0; i < 4; i++) {
      sp[i] += __shfl_xor(sp[i], off);
      dp[i] += __shfl_xor(dp[i], off);
    }
  }
  if ((t & 15) == 0) {
    #pragma unroll
    for (int i = 0; i < 4; i++) {
      st[h * NN + n0 + n4 + i] = sp[i] * LOG2E;
      dt[h * NN + n0 + n4 + i] = dp[i] * LOG2E;
    }
  }

  // stage bf16 transpose in LDS
  #pragma unroll
  for (int i = 0; i < 4; i++)
    #pragma unroll
    for (int j = 0; j < 4; j++) {
      __bf16 b = (__bf16)acc[i][j];
      lt[(k4 + j) * 64 + (n4 + i)] = __builtin_bit_cast(unsigned short, b);
    }
  __syncthreads();

  // coalesced global write of ltgT[h][k][n0..n0+64]
  const int kk = t >> 2;
  const int nc = (t & 3) * 16;
  uint4 v0 = *(const uint4*)(&lt[kk * 64 + nc]);
  uint4 v1 = *(const uint4*)(&lt[kk * 64 + nc + 8]);
  ushort* dst = ltgT + (size_t)h * FE * NN + kk * NN + n0 + nc;
  *(uint4*)(dst) = v0;
  *(uint4*)(dst + 8) = v1;
}

// ------------------------------------------------------------------
// Kernel 2: flash-style softmax(lrelu(s_i+d_j)) @ ltg via bf16 MFMA,
// j-dimension SPLIT across blockIdx.z (JC chunks) for occupancy.
// Writes fp32 partial accumulators + partial Z to workspace.
// grid (NN/64, NH, JC), 128 threads (2 waves). Wave owns 32 query rows.
// ------------------------------------------------------------------
__global__ __launch_bounds__(128, 8) void gat_k2(
    const ushort* __restrict__ ltgT, const float* __restrict__ st,
    const float* __restrict__ dt, float* __restrict__ pacc,
    float* __restrict__ zp, int JC)
{
  const int h    = blockIdx.y;
  const int i0   = blockIdx.x * 64;
  const int jc   = blockIdx.z;
  const int jlen = NN / JC;
  const int jbeg = jc * jlen;
  const int w    = threadIdx.x >> 6;
  const int lane = threadIdx.x & 63;
  const int r0   = i0 + w * 32;
  const int col  = lane & 15;
  const int koff = (lane >> 4) * 8;

  const float*  dh  = dt + h * NN;
  const ushort* lth = ltgT + (size_t)h * FE * NN;

  const float sr0 = st[h * NN + r0 + col];
  const float sr1 = st[h * NN + r0 + 16 + col];

  f32x4 acc0[4], acc1[4];
  #pragma unroll
  for (int tt = 0; tt < 4; tt++) {
    acc0[tt] = (f32x4){0.f, 0.f, 0.f, 0.f};
    acc1[tt] = (f32x4){0.f, 0.f, 0.f, 0.f};
  }
  float z0 = 0.f, z1 = 0.f;

  for (int j0 = jbeg; j0 < jbeg + jlen; j0 += 64) {
    const float* dp = dh + j0 + koff;
    float4 dA = *(const float4*)(dp);
    float4 dB = *(const float4*)(dp + 4);
    float4 dC = *(const float4*)(dp + 32);
    float4 dD = *(const float4*)(dp + 36);
    float dv[16] = {dA.x, dA.y, dA.z, dA.w, dB.x, dB.y, dB.z, dB.w,
                    dC.x, dC.y, dC.z, dC.w, dD.x, dD.y, dD.z, dD.w};

    bf16x8 af0[2], af1[2];
    #pragma unroll
    for (int ks = 0; ks < 2; ks++) {
      #pragma unroll
      for (int e = 0; e < 8; e++) {
        const float dvv = dv[ks * 8 + e];
        float x0 = sr0 + dvv;
        float p0 = exp2f(fmaxf(x0, 0.2f * x0));   // 2^(lrelu(x~))
        z0 += p0;
        af0[ks][e] = (__bf16)p0;
        float x1 = sr1 + dvv;
        float p1 = exp2f(fmaxf(x1, 0.2f * x1));
        z1 += p1;
        af1[ks][e] = (__bf16)p1;
      }
    }

    #pragma unroll
    for (int tt = 0; tt < 4; tt++) {
      #pragma unroll
      for (int ks = 0; ks < 2; ks++) {
        bf16x8 bf = *(const bf16x8*)(const void*)(lth + (size_t)(tt * 16 + col) * NN + j0 + ks * 32 + koff);
        acc0[tt] = __builtin_amdgcn_mfma_f32_16x16x32_bf16(af0[ks], bf, acc0[tt], 0, 0, 0);
        acc1[tt] = __builtin_amdgcn_mfma_f32_16x16x32_bf16(af1[ks], bf, acc1[tt], 0, 0, 0);
      }
    }
  }

  // partial Z per row: reduce lanes sharing row (lane&15)
  z0 += __shfl_xor(z0, 16); z0 += __shfl_xor(z0, 32);
  z1 += __shfl_xor(z1, 16); z1 += __shfl_xor(z1, 32);
  if (lane < 16) {
    zp[((size_t)h * NN + r0 + lane) * JC + jc]      = z0;
    zp[((size_t)h * NN + r0 + 16 + lane) * JC + jc] = z1;
  }

  // partial accumulator write (fp32, un-normalized)
  const int rquad = (lane >> 4) * 4;
  #pragma unroll
  for (int tt = 0; tt < 4; tt++) {
    #pragma unroll
    for (int reg = 0; reg < 4; reg++) {
      pacc[(((size_t)h * NN + r0 + rquad + reg) * JC + jc) * FE + tt * 16 + col]      = acc0[tt][reg];
      pacc[(((size_t)h * NN + r0 + 16 + rquad + reg) * JC + jc) * FE + tt * 16 + col] = acc1[tt][reg];
    }
  }
}

// ------------------------------------------------------------------
// Kernel 3: out[h,i,:] = (sum_c pacc[h,i,c,:]) / (sum_c zp[h,i,c])
// block = 256 threads = 4 rows; pure streaming reduce.
// ------------------------------------------------------------------
__global__ __launch_bounds__(256) void gat_k3(
    const float* __restrict__ pacc, const float* __restrict__ zp,
    float* __restrict__ out, int JC)
{
  const int t = threadIdx.x;
  const int f = t & 63;
  const size_t gi = (size_t)blockIdx.x * 4 + (t >> 6);  // h*NN+i  (0..32767)
  float s = 0.f, z = 0.f;
  for (int jc = 0; jc < JC; jc++) {
    s += pacc[(gi * JC + jc) * FE + f];
    z += zp[gi * JC + jc];
  }
  out[gi * FE + f] = s / z;
}

extern "C" void kernel_launch(void* const* d_in, const int* in_sizes, int n_in,
                              void* d_out, int out_size, void* d_ws, size_t ws_size,
                              hipStream_t stream) {
  const float* graph = (const float*)d_in[0];
  const float* W     = (const float*)d_in[1];
  const float* a     = (const float*)d_in[2];
  float* outp        = (float*)d_out;

  // workspace layout
  char* p = (char*)d_ws;
  ushort* ltgT = (ushort*)p;              p += (size_t)NH * FE * NN * 2;   // 4 MiB
  float*  st   = (float*)p;               p += (size_t)NH * NN * 4;        // 128 KiB
  float*  dtp  = (float*)p;               p += (size_t)NH * NN * 4;        // 128 KiB
  size_t used_fixed = (size_t)(p - (char*)d_ws);

  // choose JC (largest of 8/4/2/1 that fits): per-chunk cost = pacc + zp
  int JC = 1;
  for (int c = 8; c >= 1; c >>= 1) {
    size_t need = used_fixed + (size_t)c * NH * NN * (FE + 1) * 4;
    if (need <= ws_size) { JC = c; break; }
  }
  float* pacc = (float*)p;                p += (size_t)JC * NH * NN * FE * 4;
  float* zp   = (float*)p;

  dim3 g1(NN / 64, NH);
  gat_k1<<<g1, 256, 0, stream>>>(graph, W, a, ltgT, st, dtp);
  dim3 g2(NN / 64, NH, JC);
  gat_k2<<<g2, 128, 0, stream>>>(ltgT, st, dtp, pacc, zp, JC);
  dim3 g3(NH * NN / 4);
  gat_k3<<<g3, 256, 0, stream>>>(pacc, zp, outp, JC);
}

// Round 5
// 136.154 us; speedup vs baseline: 2.0661x; 2.0661x over previous
//
#include <hip/hip_runtime.h>
#include <hip/hip_bf16.h>

typedef __bf16 bf16x8 __attribute__((ext_vector_type(8)));
typedef float f32x4 __attribute__((ext_vector_type(4)));

static constexpr int NN = 4096;   // nodes
static constexpr int FE = 64;     // features
static constexpr int NH = 8;      // heads
#define LOG2E 1.44269504088896340736f

// ------------------------------------------------------------------
// Kernel 1: ltg = graph @ W[h]  (fp32), store ltgT (feature-major bf16),
//           s~ = (ltg . a_src)*log2e, d~ = (ltg . a_dst)*log2e
// grid (NN/64, NH), 256 threads
// ------------------------------------------------------------------
__global__ __launch_bounds__(256) void gat_k1(
    const float* __restrict__ graph, const float* __restrict__ W,
    const float* __restrict__ a, ushort* __restrict__ ltgT,
    float* __restrict__ st, float* __restrict__ dt)
{
  const int h  = blockIdx.y;
  const int n0 = blockIdx.x * 64;
  const int t  = threadIdx.x;

  __shared__ float  Wl[64 * 68];   // Wl[f][k], padded
  __shared__ float  gT[64 * 68];   // gT[f][n], padded (graph transposed)
  __shared__ ushort lt[64 * 64];   // lt[k][n] bf16 staging for coalesced out

  const float* Wh = W + h * FE * FE;
  const int fr = t >> 2;           // row 0..63
  const int qc = (t & 3) * 16;     // col chunk
  #pragma unroll
  for (int e = 0; e < 4; e++) {
    float4 wv = *(const float4*)(Wh + fr * FE + qc + e * 4);
    *(float4*)(&Wl[fr * 68 + qc + e * 4]) = wv;
    float4 gv = *(const float4*)(graph + (n0 + fr) * FE + qc + e * 4);
    gT[(qc + e * 4 + 0) * 68 + fr] = gv.x;
    gT[(qc + e * 4 + 1) * 68 + fr] = gv.y;
    gT[(qc + e * 4 + 2) * 68 + fr] = gv.z;
    gT[(qc + e * 4 + 3) * 68 + fr] = gv.w;
  }
  __syncthreads();

  const int n4 = (t >> 4) * 4;     // 4 nodes
  const int k4 = (t & 15) * 4;     // 4 features
  float acc[4][4];
  #pragma unroll
  for (int i = 0; i < 4; i++)
    #pragma unroll
    for (int j = 0; j < 4; j++) acc[i][j] = 0.f;

  for (int f = 0; f < FE; f++) {
    f32x4 g = *(const f32x4*)(&gT[f * 68 + n4]);
    f32x4 w = *(const f32x4*)(&Wl[f * 68 + k4]);
    #pragma unroll
    for (int i = 0; i < 4; i++)
      #pragma unroll
      for (int j = 0; j < 4; j++)
        acc[i][j] = fmaf(g[i], w[j], acc[i][j]);
  }

  // s,d partials over this thread's 4 features
  float4 As = *(const float4*)(a + h * 2 * FE + k4);
  float4 Ad = *(const float4*)(a + h * 2 * FE + FE + k4);
  float sp[4], dp[4];
  #pragma unroll
  for (int i = 0; i < 4; i++) {
    sp[i] = acc[i][0] * As.x + acc[i][1] * As.y + acc[i][2] * As.z + acc[i][3] * As.w;
    dp[i] = acc[i][0] * Ad.x + acc[i][1] * Ad.y + acc[i][2] * Ad.z + acc[i][3] * Ad.w;
  }
  #pragma unroll
  for (int off = 1; off < 16; off <<= 1) {
    #pragma unroll
    for (int i = 0; i < 4; i++) {
      sp[i] += __shfl_xor(sp[i], off);
      dp[i] += __shfl_xor(dp[i], off);
    }
  }
  if ((t & 15) == 0) {
    #pragma unroll
    for (int i = 0; i < 4; i++) {
      st[h * NN + n0 + n4 + i] = sp[i] * LOG2E;
      dt[h * NN + n0 + n4 + i] = dp[i] * LOG2E;
    }
  }

  // stage bf16 transpose in LDS
  #pragma unroll
  for (int i = 0; i < 4; i++)
    #pragma unroll
    for (int j = 0; j < 4; j++) {
      __bf16 b = (__bf16)acc[i][j];
      lt[(k4 + j) * 64 + (n4 + i)] = __builtin_bit_cast(unsigned short, b);
    }
  __syncthreads();

  // coalesced global write of ltgT[h][k][n0..n0+64]
  const int kk = t >> 2;
  const int nc = (t & 3) * 16;
  uint4 v0 = *(const uint4*)(&lt[kk * 64 + nc]);
  uint4 v1 = *(const uint4*)(&lt[kk * 64 + nc + 8]);
  ushort* dst = ltgT + (size_t)h * FE * NN + kk * NN + n0 + nc;
  *(uint4*)(dst) = v0;
  *(uint4*)(dst + 8) = v1;
}

// ------------------------------------------------------------------
// Kernel 2: flash-style softmax(lrelu(s_i+d_j)) @ ltg via bf16 MFMA.
// Block = 8 waves, i-tile of 32 rows; j split ACROSS THE 8 WAVES
// (512-j chunk each), partials reduced in LDS (no global partial traffic).
// grid (NN/32, NH). Each wave: 32 rows x its 512-j chunk.
// A-frag (16x16x32): row = lane&15, k = (lane>>4)*8 + e.
// C/D: col = lane&15, row = (lane>>4)*4 + reg.
// ------------------------------------------------------------------
__global__ __launch_bounds__(512) void gat_k2(
    const ushort* __restrict__ ltgT, const float* __restrict__ st,
    const float* __restrict__ dt, float* __restrict__ out)
{
  const int h    = blockIdx.y;
  const int i0   = blockIdx.x * 32;
  const int w    = threadIdx.x >> 6;     // wave 0..7 -> j chunk
  const int lane = threadIdx.x & 63;
  const int col  = lane & 15;
  const int koff = (lane >> 4) * 8;

  __shared__ float lds_pacc[8][32 * 65]; // stride 65: breaks 4-way bank conflict
  __shared__ float lds_z[8][32];

  const float*  dh  = dt + h * NN;
  const ushort* lth = ltgT + (size_t)h * FE * NN;

  const float sr0 = st[h * NN + i0 + col];
  const float sr1 = st[h * NN + i0 + 16 + col];

  f32x4 acc0[4], acc1[4];
  #pragma unroll
  for (int tt = 0; tt < 4; tt++) {
    acc0[tt] = (f32x4){0.f, 0.f, 0.f, 0.f};
    acc1[tt] = (f32x4){0.f, 0.f, 0.f, 0.f};
  }
  float z0 = 0.f, z1 = 0.f;

  const int jbeg = w * (NN / 8);
  for (int j0 = jbeg; j0 < jbeg + NN / 8; j0 += 64) {
    const float* dp = dh + j0 + koff;
    float4 dA = *(const float4*)(dp);
    float4 dB = *(const float4*)(dp + 4);
    float4 dC = *(const float4*)(dp + 32);
    float4 dD = *(const float4*)(dp + 36);
    float dv[16] = {dA.x, dA.y, dA.z, dA.w, dB.x, dB.y, dB.z, dB.w,
                    dC.x, dC.y, dC.z, dC.w, dD.x, dD.y, dD.z, dD.w};

    bf16x8 af0[2], af1[2];
    #pragma unroll
    for (int ks = 0; ks < 2; ks++) {
      #pragma unroll
      for (int e = 0; e < 8; e++) {
        const float dvv = dv[ks * 8 + e];
        float x0 = sr0 + dvv;
        float p0 = exp2f(fmaxf(x0, 0.2f * x0));   // 2^(lrelu(x~))
        z0 += p0;
        af0[ks][e] = (__bf16)p0;
        float x1 = sr1 + dvv;
        float p1 = exp2f(fmaxf(x1, 0.2f * x1));
        z1 += p1;
        af1[ks][e] = (__bf16)p1;
      }
    }

    #pragma unroll
    for (int tt = 0; tt < 4; tt++) {
      #pragma unroll
      for (int ks = 0; ks < 2; ks++) {
        bf16x8 bf = *(const bf16x8*)(const void*)(lth + (size_t)(tt * 16 + col) * NN + j0 + ks * 32 + koff);
        acc0[tt] = __builtin_amdgcn_mfma_f32_16x16x32_bf16(af0[ks], bf, acc0[tt], 0, 0, 0);
        acc1[tt] = __builtin_amdgcn_mfma_f32_16x16x32_bf16(af1[ks], bf, acc1[tt], 0, 0, 0);
      }
    }
  }

  // wave-partial Z per row (rows 0..15 in z0, 16..31 in z1)
  z0 += __shfl_xor(z0, 16); z0 += __shfl_xor(z0, 32);
  z1 += __shfl_xor(z1, 16); z1 += __shfl_xor(z1, 32);
  if (lane < 16) {
    lds_z[w][lane]      = z0;
    lds_z[w][16 + lane] = z1;
  }

  // wave-partial accumulators to LDS
  const int rquad = (lane >> 4) * 4;
  #pragma unroll
  for (int tt = 0; tt < 4; tt++) {
    #pragma unroll
    for (int reg = 0; reg < 4; reg++) {
      lds_pacc[w][(rquad + reg) * 65 + tt * 16 + col]      = acc0[tt][reg];
      lds_pacc[w][(16 + rquad + reg) * 65 + tt * 16 + col] = acc1[tt][reg];
    }
  }
  __syncthreads();

  // cross-wave reduce: thread t -> row r = t>>4, features f4 = (t&15)*4
  const int r  = threadIdx.x >> 4;
  const int f4 = (threadIdx.x & 15) * 4;
  float s0 = 0.f, s1 = 0.f, s2 = 0.f, s3 = 0.f, zz = 0.f;
  #pragma unroll
  for (int ww = 0; ww < 8; ww++) {
    const float* pp = &lds_pacc[ww][r * 65 + f4];
    s0 += pp[0]; s1 += pp[1]; s2 += pp[2]; s3 += pp[3];
    zz += lds_z[ww][r];
  }
  const float inv = 1.f / zz;
  float4 o = {s0 * inv, s1 * inv, s2 * inv, s3 * inv};
  *(float4*)(&out[((size_t)h * NN + i0 + r) * FE + f4]) = o;
}

extern "C" void kernel_launch(void* const* d_in, const int* in_sizes, int n_in,
                              void* d_out, int out_size, void* d_ws, size_t ws_size,
                              hipStream_t stream) {
  const float* graph = (const float*)d_in[0];
  const float* W     = (const float*)d_in[1];
  const float* a     = (const float*)d_in[2];
  float* outp        = (float*)d_out;

  // workspace layout (4.25 MiB total)
  char* p = (char*)d_ws;
  ushort* ltgT = (ushort*)p;              p += (size_t)NH * FE * NN * 2;   // 4 MiB
  float*  st   = (float*)p;               p += (size_t)NH * NN * 4;        // 128 KiB
  float*  dtp  = (float*)p;               p += (size_t)NH * NN * 4;        // 128 KiB

  dim3 g1(NN / 64, NH);
  gat_k1<<<g1, 256, 0, stream>>>(graph, W, a, ltgT, st, dtp);
  dim3 g2(NN / 32, NH);
  gat_k2<<<g2, 512, 0, stream>>>(ltgT, st, dtp, outp);
}

// Round 8
// 135.653 us; speedup vs baseline: 2.0737x; 1.0037x over previous
//
#include <hip/hip_runtime.h>
#include <hip/hip_bf16.h>

typedef __bf16 bf16x8 __attribute__((ext_vector_type(8)));
typedef float f32x4 __attribute__((ext_vector_type(4)));

static constexpr int NN = 4096;   // nodes
static constexpr int FE = 64;     // features
static constexpr int NH = 8;      // heads
#define LOG2E 1.44269504088896340736f

#if __has_builtin(__builtin_amdgcn_exp2f)
#define EXP2F(x) __builtin_amdgcn_exp2f(x)
#else
#define EXP2F(x) exp2f(x)
#endif

// ------------------------------------------------------------------
// Kernel 1: ltg = graph @ W[h]  (fp32), store ltgT (feature-major bf16),
//           s~ = (ltg . a_src)*log2e, d~ = (ltg . a_dst)*log2e
// grid (NN/64, NH), 256 threads   [unchanged from round 5]
// ------------------------------------------------------------------
__global__ __launch_bounds__(256) void gat_k1(
    const float* __restrict__ graph, const float* __restrict__ W,
    const float* __restrict__ a, ushort* __restrict__ ltgT,
    float* __restrict__ st, float* __restrict__ dt)
{
  const int h  = blockIdx.y;
  const int n0 = blockIdx.x * 64;
  const int t  = threadIdx.x;

  __shared__ float  Wl[64 * 68];   // Wl[f][k], padded
  __shared__ float  gT[64 * 68];   // gT[f][n], padded (graph transposed)
  __shared__ ushort lt[64 * 64];   // lt[k][n] bf16 staging for coalesced out

  const float* Wh = W + h * FE * FE;
  const int fr = t >> 2;           // row 0..63
  const int qc = (t & 3) * 16;     // col chunk
  #pragma unroll
  for (int e = 0; e < 4; e++) {
    float4 wv = *(const float4*)(Wh + fr * FE + qc + e * 4);
    *(float4*)(&Wl[fr * 68 + qc + e * 4]) = wv;
    float4 gv = *(const float4*)(graph + (n0 + fr) * FE + qc + e * 4);
    gT[(qc + e * 4 + 0) * 68 + fr] = gv.x;
    gT[(qc + e * 4 + 1) * 68 + fr] = gv.y;
    gT[(qc + e * 4 + 2) * 68 + fr] = gv.z;
    gT[(qc + e * 4 + 3) * 68 + fr] = gv.w;
  }
  __syncthreads();

  const int n4 = (t >> 4) * 4;     // 4 nodes
  const int k4 = (t & 15) * 4;     // 4 features
  float acc[4][4];
  #pragma unroll
  for (int i = 0; i < 4; i++)
    #pragma unroll
    for (int j = 0; j < 4; j++) acc[i][j] = 0.f;

  for (int f = 0; f < FE; f++) {
    f32x4 g = *(const f32x4*)(&gT[f * 68 + n4]);
    f32x4 w = *(const f32x4*)(&Wl[f * 68 + k4]);
    #pragma unroll
    for (int i = 0; i < 4; i++)
      #pragma unroll
      for (int j = 0; j < 4; j++)
        acc[i][j] = fmaf(g[i], w[j], acc[i][j]);
  }

  // s,d partials over this thread's 4 features
  float4 As = *(const float4*)(a + h * 2 * FE + k4);
  float4 Ad = *(const float4*)(a + h * 2 * FE + FE + k4);
  float sp[4], dp[4];
  #pragma unroll
  for (int i = 0; i < 4; i++) {
    sp[i] = acc[i][0] * As.x + acc[i][1] * As.y + acc[i][2] * As.z + acc[i][3] * As.w;
    dp[i] = acc[i][0] * Ad.x + acc[i][1] * Ad.y + acc[i][2] * Ad.z + acc[i][3] * Ad.w;
  }
  #pragma unroll
  for (int off = 1; off < 16; off <<= 1) {
    #pragma unroll
    for (int i = 0; i < 4; i++) {
      sp[i] += __shfl_xor(sp[i], off);
      dp[i] += __shfl_xor(dp[i], off);
    }
  }
  if ((t & 15) == 0) {
    #pragma unroll
    for (int i = 0; i < 4; i++) {
      st[h * NN + n0 + n4 + i] = sp[i] * LOG2E;
      dt[h * NN + n0 + n4 + i] = dp[i] * LOG2E;
    }
  }

  // stage bf16 transpose in LDS
  #pragma unroll
  for (int i = 0; i < 4; i++)
    #pragma unroll
    for (int j = 0; j < 4; j++) {
      __bf16 b = (__bf16)acc[i][j];
      lt[(k4 + j) * 64 + (n4 + i)] = __builtin_bit_cast(unsigned short, b);
    }
  __syncthreads();

  // coalesced global write of ltgT[h][k][n0..n0+64]
  const int kk = t >> 2;
  const int nc = (t & 3) * 16;
  uint4 v0 = *(const uint4*)(&lt[kk * 64 + nc]);
  uint4 v1 = *(const uint4*)(&lt[kk * 64 + nc + 8]);
  ushort* dst = ltgT + (size_t)h * FE * NN + kk * NN + n0 + nc;
  *(uint4*)(dst) = v0;
  *(uint4*)(dst + 8) = v1;
}

// ------------------------------------------------------------------
// Kernel 2: flash-style softmax(lrelu(s_i+d_j)) @ ltg via bf16 MFMA.
// Block = 4 waves (256 thr), i-tile 32 rows; j split across the 4 waves
// (1024-j chunk each), partials reduced in LDS.
// Z computed via ones-vector MFMA (denominator shares P's bf16 quant).
// grid (NN/32, NH) = 1024 blocks = exactly 4/CU -> full residency.
// A-frag (16x16x32): row = lane&15, k = (lane>>4)*8 + e.
// C/D: col = lane&15, row = (lane>>4)*4 + reg.
// ------------------------------------------------------------------
__global__ __launch_bounds__(256) void gat_k2(
    const ushort* __restrict__ ltgT, const float* __restrict__ st,
    const float* __restrict__ dt, float* __restrict__ out)
{
  const int h    = blockIdx.y;
  const int i0   = blockIdx.x * 32;
  const int w    = threadIdx.x >> 6;     // wave 0..3 -> j chunk
  const int lane = threadIdx.x & 63;
  const int col  = lane & 15;
  const int koff = (lane >> 4) * 8;

  __shared__ float lds_pacc[4][32 * 68]; // stride 68 (==4 mod 32): 2-way max, 16B aligned
  __shared__ float lds_z[4][32];

  const float*  dh  = dt + h * NN;
  const ushort* lth = ltgT + (size_t)h * FE * NN;

  const float sr0 = st[h * NN + i0 + col];
  const float sr1 = st[h * NN + i0 + 16 + col];

  f32x4 acc0[4], acc1[4], accZ0, accZ1;
  #pragma unroll
  for (int tt = 0; tt < 4; tt++) {
    acc0[tt] = (f32x4){0.f, 0.f, 0.f, 0.f};
    acc1[tt] = (f32x4){0.f, 0.f, 0.f, 0.f};
  }
  accZ0 = (f32x4){0.f, 0.f, 0.f, 0.f};
  accZ1 = (f32x4){0.f, 0.f, 0.f, 0.f};

  bf16x8 ones;
  #pragma unroll
  for (int e = 0; e < 8; e++) ones[e] = (__bf16)1.0f;

  const int jbeg = w * (NN / 4);
  for (int j0 = jbeg; j0 < jbeg + NN / 4; j0 += 64) {
    const float* dp = dh + j0 + koff;
    float4 dA = *(const float4*)(dp);
    float4 dB = *(const float4*)(dp + 4);
    float4 dC = *(const float4*)(dp + 32);
    float4 dD = *(const float4*)(dp + 36);
    float dv[16] = {dA.x, dA.y, dA.z, dA.w, dB.x, dB.y, dB.z, dB.w,
                    dC.x, dC.y, dC.z, dC.w, dD.x, dD.y, dD.z, dD.w};

    bf16x8 af0[2], af1[2];
    #pragma unroll
    for (int ks = 0; ks < 2; ks++) {
      #pragma unroll
      for (int e = 0; e < 8; e++) {
        const float dvv = dv[ks * 8 + e];
        float x0 = sr0 + dvv;
        float p0 = EXP2F(fmaxf(x0, 0.2f * x0));   // 2^(lrelu(x~))
        af0[ks][e] = (__bf16)p0;
        float x1 = sr1 + dvv;
        float p1 = EXP2F(fmaxf(x1, 0.2f * x1));
        af1[ks][e] = (__bf16)p1;
      }
    }

    #pragma unroll
    for (int tt = 0; tt < 4; tt++) {
      #pragma unroll
      for (int ks = 0; ks < 2; ks++) {
        bf16x8 bf = *(const bf16x8*)(const void*)(lth + (size_t)(tt * 16 + col) * NN + j0 + ks * 32 + koff);
        acc0[tt] = __builtin_amdgcn_mfma_f32_16x16x32_bf16(af0[ks], bf, acc0[tt], 0, 0, 0);
        acc1[tt] = __builtin_amdgcn_mfma_f32_16x16x32_bf16(af1[ks], bf, acc1[tt], 0, 0, 0);
      }
    }
    #pragma unroll
    for (int ks = 0; ks < 2; ks++) {
      accZ0 = __builtin_amdgcn_mfma_f32_16x16x32_bf16(af0[ks], ones, accZ0, 0, 0, 0);
      accZ1 = __builtin_amdgcn_mfma_f32_16x16x32_bf16(af1[ks], ones, accZ1, 0, 0, 0);
    }
  }

  // wave-partial Z per row: every col holds the same row-sum; col 0 writes
  const int rquad = (lane >> 4) * 4;
  if (col == 0) {
    #pragma unroll
    for (int reg = 0; reg < 4; reg++) {
      lds_z[w][rquad + reg]      = accZ0[reg];
      lds_z[w][16 + rquad + reg] = accZ1[reg];
    }
  }

  // wave-partial accumulators to LDS
  #pragma unroll
  for (int tt = 0; tt < 4; tt++) {
    #pragma unroll
    for (int reg = 0; reg < 4; reg++) {
      lds_pacc[w][(rquad + reg) * 68 + tt * 16 + col]      = acc0[tt][reg];
      lds_pacc[w][(16 + rquad + reg) * 68 + tt * 16 + col] = acc1[tt][reg];
    }
  }
  __syncthreads();

  // cross-wave reduce: thread t -> row r = t>>3, features f8 = (t&7)*8
  const int r  = threadIdx.x >> 3;
  const int f8 = (threadIdx.x & 7) * 8;
  f32x4 sA = (f32x4){0.f, 0.f, 0.f, 0.f};
  f32x4 sB = (f32x4){0.f, 0.f, 0.f, 0.f};
  float zz = 0.f;
  #pragma unroll
  for (int ww = 0; ww < 4; ww++) {
    const float* pp = &lds_pacc[ww][r * 68 + f8];
    f32x4 vA = *(const f32x4*)(pp);
    f32x4 vB = *(const f32x4*)(pp + 4);
    sA += vA; sB += vB;
    zz += lds_z[ww][r];
  }
  const float inv = 1.f / zz;
  float* orow = &out[((size_t)h * NN + i0 + r) * FE + f8];
  f32x4 oA = {sA[0] * inv, sA[1] * inv, sA[2] * inv, sA[3] * inv};
  f32x4 oB = {sB[0] * inv, sB[1] * inv, sB[2] * inv, sB[3] * inv};
  *(f32x4*)(orow)     = oA;
  *(f32x4*)(orow + 4) = oB;
}

extern "C" void kernel_launch(void* const* d_in, const int* in_sizes, int n_in,
                              void* d_out, int out_size, void* d_ws, size_t ws_size,
                              hipStream_t stream) {
  const float* graph = (const float*)d_in[0];
  const float* W     = (const float*)d_in[1];
  const float* a     = (const float*)d_in[2];
  float* outp        = (float*)d_out;

  // workspace layout (4.25 MiB total)
  char* p = (char*)d_ws;
  ushort* ltgT = (ushort*)p;              p += (size_t)NH * FE * NN * 2;   // 4 MiB
  float*  st   = (float*)p;               p += (size_t)NH * NN * 4;        // 128 KiB
  float*  dtp  = (float*)p;               p += (size_t)NH * NN * 4;        // 128 KiB

  dim3 g1(NN / 64, NH);
  gat_k1<<<g1, 256, 0, stream>>>(graph, W, a, ltgT, st, dtp);
  dim3 g2(NN / 32, NH);
  gat_k2<<<g2, 256, 0, stream>>>(ltgT, st, dtp, outp);
}